// Round 11
// baseline (97.377 us; speedup 1.0000x reference)
//
#include <hip/hip_runtime.h>

#define DD 64
#define BSH 6                   // 64 nodes per bucket
#define GBKT 64
#define CAP 1280                // edge capacity per bucket region (mean 1024, +8 sigma)
#define TILE 4096               // edges per partition block
#define PTHREADS 512            // part_k block size
#define MAXBK 1600              // part_k LDS arrays sized for NBK <= 1600

__device__ __forceinline__ float bflo(unsigned int u) {
    return __uint_as_float(u << 16);
}
__device__ __forceinline__ float bfhi(unsigned int u) {
    return __uint_as_float(u & 0xffff0000u);
}
__device__ __forceinline__ unsigned short f2bf(float f) {   // RNE
    unsigned int b = __float_as_uint(f);
    return (unsigned short)((b + 0x7fffu + ((b >> 16) & 1u)) >> 16);
}
// acc += bf16row(r) * s
__device__ __forceinline__ void fma_row(uint4 r, float s, float4& lo, float4& hi) {
    lo.x = fmaf(bflo(r.x), s, lo.x); lo.y = fmaf(bfhi(r.x), s, lo.y);
    lo.z = fmaf(bflo(r.y), s, lo.z); lo.w = fmaf(bfhi(r.y), s, lo.w);
    hi.x = fmaf(bflo(r.z), s, hi.x); hi.y = fmaf(bfhi(r.z), s, hi.y);
    hi.z = fmaf(bflo(r.w), s, hi.z); hi.w = fmaf(bfhi(r.w), s, hi.w);
}

// ---------------- y = bf16(z @ W^T) (unscaled) + bcur init ----------------
__global__ __launch_bounds__(512) void gemm_k(const float* __restrict__ z,
                                              const float* __restrict__ W,
                                              ushort4* __restrict__ ybf,
                                              int* __restrict__ bcur,
                                              int N, int NBK) {
    int tid = threadIdx.x;
    int gid = blockIdx.x * 512 + tid;
    if (gid < NBK) bcur[gid] = gid * CAP;   // fold init: runs before part_k

    __shared__ float Wt[64 * 68];
    __shared__ float zt[32 * 68];
    for (int i = tid; i < DD * DD; i += 512) {
        int d = i >> 6, k = i & 63;
        Wt[k * 68 + d] = W[i];
    }
    {
        int zr = blockIdx.x * 32 + (tid >> 4);
        float4 v = (zr < N) ? reinterpret_cast<const float4*>(z)[(size_t)zr * 16 + (tid & 15)]
                            : make_float4(0.f, 0.f, 0.f, 0.f);
        *reinterpret_cast<float4*>(&zt[(tid >> 4) * 68 + (tid & 15) * 4]) = v;
    }
    __syncthreads();
    int r = tid >> 4;
    int c = tid & 15;
    int row = blockIdx.x * 32 + r;
    float4 acc = make_float4(0.f, 0.f, 0.f, 0.f);
    #pragma unroll
    for (int k = 0; k < DD; ++k) {
        float zv = zt[r * 68 + k];
        float4 w = *reinterpret_cast<const float4*>(&Wt[k * 68 + c * 4]);
        acc.x = fmaf(zv, w.x, acc.x);
        acc.y = fmaf(zv, w.y, acc.y);
        acc.z = fmaf(zv, w.z, acc.z);
        acc.w = fmaf(zv, w.w, acc.w);
    }
    if (row < N) {
        ushort4 o;
        o.x = f2bf(acc.x);
        o.y = f2bf(acc.y);
        o.z = f2bf(acc.z);
        o.w = f2bf(acc.w);
        ybf[(size_t)row * 16 + c] = o;
    }
}

// ---------------- bucketed partition into capacity-slotted regions ----------------
// packed = (src << BSH) | (dst & (GBKT-1))
__global__ __launch_bounds__(PTHREADS) void part_k(const int* __restrict__ src,
                                                   const int* __restrict__ dst,
                                                   int* __restrict__ bcur,
                                                   int* __restrict__ bp,
                                                   int E, int NBK) {
    __shared__ int hist[MAXBK];
    __shared__ int scanb[MAXBK];
    __shared__ int gbase[MAXBK];
    __shared__ int stage[TILE];             // 16 KB packed
    __shared__ unsigned short bstage[TILE]; // 8 KB bucket ids

    int tid = threadIdx.x;
    int tbase = blockIdx.x * TILE;
    int n = E - tbase;
    if (n > TILE) n = TILE;

    for (int i = tid; i < NBK; i += PTHREADS) hist[i] = 0;
    __syncthreads();

    int pv[TILE / PTHREADS];
    int pb[TILE / PTHREADS];
    #pragma unroll
    for (int e = 0; e < TILE / PTHREADS; ++e) {
        int i = tid + e * PTHREADS;
        pb[e] = -1;
        if (i < n) {
            int s = src[tbase + i];
            int d = dst[tbase + i];
            pv[e] = (s << BSH) | (d & (GBKT - 1));
            pb[e] = d >> BSH;
            atomicAdd(&hist[pb[e]], 1);
        }
    }
    __syncthreads();

    // one-wave chunked exclusive scan of hist -> scanb
    if (tid < 64) {
        int run = 0;
        for (int base = 0; base < NBK; base += 64) {
            int i = base + tid;
            int orig = (i < NBK) ? hist[i] : 0;
            int v = orig;
            #pragma unroll
            for (int off = 1; off < 64; off <<= 1) {
                int t = __shfl_up(v, off, 64);
                if (tid >= off) v += t;
            }
            if (i < NBK) scanb[i] = run + v - orig;
            run += __shfl(v, 63, 64);
        }
    }
    __syncthreads();

    // reserve ranges in each bucket's region
    for (int i = tid; i < NBK; i += PTHREADS)
        if (hist[i]) gbase[i] = atomicAdd(&bcur[i], hist[i]);
    __syncthreads();
    for (int i = tid; i < NBK; i += PTHREADS) hist[i] = scanb[i];  // staging cursor
    __syncthreads();

    #pragma unroll
    for (int e = 0; e < TILE / PTHREADS; ++e) {
        if (pb[e] >= 0) {
            int r = atomicAdd(&hist[pb[e]], 1);
            stage[r] = pv[e];
            bstage[r] = (unsigned short)pb[e];
        }
    }
    __syncthreads();

    // contiguous runs per bucket
    for (int i = tid; i < n; i += PTHREADS) {
        int b = bstage[i];
        bp[gbase[b] + (i - scanb[b])] = stage[i];
    }
}

// ---------------- per-bucket node degrees -> dinv ----------------
__global__ void nodedeg_k(const int* __restrict__ bp, const int* __restrict__ bcur,
                          float* __restrict__ dinv, int N) {
    __shared__ int cnt[GBKT];
    int k = blockIdx.x;
    int tid = threadIdx.x;
    int ebeg = k * CAP;
    int eend = bcur[k];
    if (tid < GBKT) cnt[tid] = 0;
    __syncthreads();
    for (int i = ebeg + tid; i < eend; i += 256)
        atomicAdd(&cnt[bp[i] & (GBKT - 1)], 1);
    __syncthreads();
    if (tid < GBKT) {
        int node = (k << BSH) + tid;
        if (node < N) dinv[node] = rsqrtf((float)(1 + cnt[tid]));
    }
}

// ---------------- fused per-bucket LDS sort + gather + epilogue ----------------
// one block per 64-node bucket; 8-lane group per node, 8-deep load pipeline.
// out[n] = relu( dinv[n] * ( y[n]*dinv[n] + sum_s y[s]*dinv[s] ) + b )
__global__ __launch_bounds__(256) void bg_k(const uint4* __restrict__ ybf,
                                            const float* __restrict__ dinv,
                                            const int* __restrict__ bp,
                                            const int* __restrict__ bcur,
                                            const float4* __restrict__ b4,
                                            float4* __restrict__ out4, int N) {
    __shared__ int cnt[GBKT];
    __shared__ int excl[GBKT];
    __shared__ int cur[GBKT];
    __shared__ int sorted[CAP];   // 5 KB: src ids sorted by local dst
    __shared__ int nextn;
    int k = blockIdx.x;
    int tid = threadIdx.x;
    int ebeg = k * CAP;
    int eend = bcur[k];
    int base = k << BSH;

    if (tid < GBKT) cnt[tid] = 0;
    if (tid == 0) nextn = 0;
    __syncthreads();
    for (int i = ebeg + tid; i < eend; i += 256)
        atomicAdd(&cnt[bp[i] & (GBKT - 1)], 1);
    __syncthreads();

    // wave 0: 64-wide shfl exclusive scan of the 64 counters
    if (tid < 64) {
        int c0 = cnt[tid];
        int v = c0;
        #pragma unroll
        for (int off = 1; off < 64; off <<= 1) {
            int t = __shfl_up(v, off, 64);
            if (tid >= off) v += t;
        }
        excl[tid] = v - c0;
        cur[tid] = v - c0;
    }
    __syncthreads();

    // counting-sort fill into LDS (local positions)
    for (int i = ebeg + tid; i < eend; i += 256) {
        int v = bp[i];
        int l = v & (GBKT - 1);
        int pos = atomicAdd(&cur[l], 1);
        sorted[pos] = v >> BSH;     // global src index
    }
    __syncthreads();

    // gather: 8-lane groups pull node slots dynamically
    int lane = tid & 63;
    int c = tid & 7;            // col block (8 bf16 cols = 16B)
    for (;;) {
        int slot;
        if ((tid & 7) == 0) slot = atomicAdd(&nextn, 1);
        slot = __shfl(slot, lane & 56, 64);
        if (slot >= GBKT) break;
        int node = base + slot;
        if (node >= N) continue;
        int beg = excl[slot];
        int cn = cnt[slot];
        int end = beg + cn;
        float dn = rsqrtf((float)(1 + cn));
        float4 a0 = make_float4(0.f, 0.f, 0.f, 0.f), a1 = a0;
        float4 e0 = a0, e1 = a0;
        // self-loop message: y[n]*dinv[n]
        fma_row(ybf[(size_t)node * 8 + c], dn, a0, a1);
        int j = beg;
        for (; j + 7 < end; j += 8) {   // 8-deep: batch ss, dinv, rows
            int s0 = sorted[j],     s1 = sorted[j + 1], s2 = sorted[j + 2], s3 = sorted[j + 3];
            int s4 = sorted[j + 4], s5 = sorted[j + 5], s6 = sorted[j + 6], s7 = sorted[j + 7];
            float d0 = dinv[s0], d1 = dinv[s1], d2 = dinv[s2], d3 = dinv[s3];
            float d4 = dinv[s4], d5 = dinv[s5], d6 = dinv[s6], d7 = dinv[s7];
            uint4 r0 = ybf[(size_t)s0 * 8 + c];
            uint4 r1 = ybf[(size_t)s1 * 8 + c];
            uint4 r2 = ybf[(size_t)s2 * 8 + c];
            uint4 r3 = ybf[(size_t)s3 * 8 + c];
            uint4 r4 = ybf[(size_t)s4 * 8 + c];
            uint4 r5 = ybf[(size_t)s5 * 8 + c];
            uint4 r6 = ybf[(size_t)s6 * 8 + c];
            uint4 r7 = ybf[(size_t)s7 * 8 + c];
            fma_row(r0, d0, a0, a1);
            fma_row(r1, d1, e0, e1);
            fma_row(r2, d2, a0, a1);
            fma_row(r3, d3, e0, e1);
            fma_row(r4, d4, a0, a1);
            fma_row(r5, d5, e0, e1);
            fma_row(r6, d6, a0, a1);
            fma_row(r7, d7, e0, e1);
        }
        for (; j + 3 < end; j += 4) {   // 4-deep tail
            int s0 = sorted[j], s1 = sorted[j + 1], s2 = sorted[j + 2], s3 = sorted[j + 3];
            float d0 = dinv[s0], d1 = dinv[s1], d2 = dinv[s2], d3 = dinv[s3];
            uint4 r0 = ybf[(size_t)s0 * 8 + c];
            uint4 r1 = ybf[(size_t)s1 * 8 + c];
            uint4 r2 = ybf[(size_t)s2 * 8 + c];
            uint4 r3 = ybf[(size_t)s3 * 8 + c];
            fma_row(r0, d0, a0, a1);
            fma_row(r1, d1, e0, e1);
            fma_row(r2, d2, a0, a1);
            fma_row(r3, d3, e0, e1);
        }
        for (; j < end; ++j) {
            int s = sorted[j];
            fma_row(ybf[(size_t)s * 8 + c], dinv[s], a0, a1);
        }
        a0.x += e0.x; a0.y += e0.y; a0.z += e0.z; a0.w += e0.w;
        a1.x += e1.x; a1.y += e1.y; a1.z += e1.z; a1.w += e1.w;

        float4 bb0 = b4[2 * c];
        float4 bb1 = b4[2 * c + 1];
        float4 o0, o1;
        o0.x = fmaxf(fmaf(a0.x, dn, bb0.x), 0.f);
        o0.y = fmaxf(fmaf(a0.y, dn, bb0.y), 0.f);
        o0.z = fmaxf(fmaf(a0.z, dn, bb0.z), 0.f);
        o0.w = fmaxf(fmaf(a0.w, dn, bb0.w), 0.f);
        o1.x = fmaxf(fmaf(a1.x, dn, bb1.x), 0.f);
        o1.y = fmaxf(fmaf(a1.y, dn, bb1.y), 0.f);
        o1.z = fmaxf(fmaf(a1.z, dn, bb1.z), 0.f);
        o1.w = fmaxf(fmaf(a1.w, dn, bb1.w), 0.f);
        out4[(size_t)node * 16 + 2 * c] = o0;
        out4[(size_t)node * 16 + 2 * c + 1] = o1;
    }
}

// ---------------- launch ----------------

extern "C" void kernel_launch(void* const* d_in, const int* in_sizes, int n_in,
                              void* d_out, int out_size, void* d_ws, size_t ws_size,
                              hipStream_t stream) {
    const float* z = (const float*)d_in[0];
    const int* ei  = (const int*)d_in[1];
    const float* W = (const float*)d_in[2];
    const float* b = (const float*)d_in[3];
    float* out = (float*)d_out;

    const int N = in_sizes[0] / DD;
    const int E = in_sizes[1] / 2;
    const int* src = ei;
    const int* dst = ei + E;

    const int NBK = (N + GBKT - 1) >> BSH;

    // workspace layout
    unsigned short* ybf = (unsigned short*)d_ws;      // 64N ushorts (bf16)
    float* dinv  = (float*)(ybf + (size_t)64 * N);    // N f
    int*   bcur  = (int*)(dinv + N);                  // NBK
    int*   bp    = bcur + NBK;                        // NBK*CAP

    gemm_k<<<(N + 31) / 32, 512, 0, stream>>>(z, W, (ushort4*)ybf, bcur, N, NBK);
    part_k<<<(E + TILE - 1) / TILE, PTHREADS, 0, stream>>>(src, dst, bcur, bp, E, NBK);
    nodedeg_k<<<NBK, 256, 0, stream>>>(bp, bcur, dinv, N);
    bg_k<<<NBK, 256, 0, stream>>>((const uint4*)ybf, dinv, bp, bcur,
                                  (const float4*)b, (float4*)out, N);
}

// Round 12
// 95.735 us; speedup vs baseline: 1.0172x; 1.0172x over previous
//
#include <hip/hip_runtime.h>

#define DD 64
#define BSH 7                   // 128 nodes per bucket
#define GBKT 128
#define CAP 2560                // edge capacity per bucket region (mean 2046, +11 sigma)
#define TILE 4096               // edges per partition block
#define PTHREADS 512            // part_k block size
#define MAXBK 1024              // part_k LDS arrays sized for NBK <= 1024

__device__ __forceinline__ float bflo(unsigned int u) {
    return __uint_as_float(u << 16);
}
__device__ __forceinline__ float bfhi(unsigned int u) {
    return __uint_as_float(u & 0xffff0000u);
}
__device__ __forceinline__ unsigned short f2bf(float f) {   // RNE
    unsigned int b = __float_as_uint(f);
    return (unsigned short)((b + 0x7fffu + ((b >> 16) & 1u)) >> 16);
}
__device__ __forceinline__ void acc_row(uint4 r, float4& lo, float4& hi) {
    lo.x += bflo(r.x); lo.y += bfhi(r.x);
    lo.z += bflo(r.y); lo.w += bfhi(r.y);
    hi.x += bflo(r.z); hi.y += bfhi(r.z);
    hi.z += bflo(r.w); hi.w += bfhi(r.w);
}

// ---------------- init per-bucket cursors to region bases ----------------
__global__ void init_k(int* __restrict__ bcur, int NBK) {
    int i = blockIdx.x * blockDim.x + threadIdx.x;
    if (i < NBK) bcur[i] = i * CAP;
}

// ---------------- bucketed partition into capacity-slotted regions ----------------
// packed = (src << BSH) | (dst & (GBKT-1))
__global__ __launch_bounds__(PTHREADS) void part_k(const int* __restrict__ src,
                                                   const int* __restrict__ dst,
                                                   int* __restrict__ bcur,
                                                   int* __restrict__ bp,
                                                   int E, int NBK) {
    __shared__ int hist[MAXBK];
    __shared__ int scanb[MAXBK];
    __shared__ int gbase[MAXBK];
    __shared__ int stage[TILE];             // 16 KB packed
    __shared__ unsigned short bstage[TILE]; // 8 KB bucket ids

    int tid = threadIdx.x;
    int tbase = blockIdx.x * TILE;
    int n = E - tbase;
    if (n > TILE) n = TILE;

    for (int i = tid; i < NBK; i += PTHREADS) hist[i] = 0;
    __syncthreads();

    int pv[TILE / PTHREADS];
    int pb[TILE / PTHREADS];
    #pragma unroll
    for (int e = 0; e < TILE / PTHREADS; ++e) {
        int i = tid + e * PTHREADS;
        pb[e] = -1;
        if (i < n) {
            int s = src[tbase + i];
            int d = dst[tbase + i];
            pv[e] = (s << BSH) | (d & (GBKT - 1));
            pb[e] = d >> BSH;
            atomicAdd(&hist[pb[e]], 1);
        }
    }
    __syncthreads();

    // one-wave chunked exclusive scan of hist -> scanb
    if (tid < 64) {
        int run = 0;
        for (int base = 0; base < NBK; base += 64) {
            int i = base + tid;
            int orig = (i < NBK) ? hist[i] : 0;
            int v = orig;
            #pragma unroll
            for (int off = 1; off < 64; off <<= 1) {
                int t = __shfl_up(v, off, 64);
                if (tid >= off) v += t;
            }
            if (i < NBK) scanb[i] = run + v - orig;
            run += __shfl(v, 63, 64);
        }
    }
    __syncthreads();

    // reserve ranges in each bucket's region
    for (int i = tid; i < NBK; i += PTHREADS)
        if (hist[i]) gbase[i] = atomicAdd(&bcur[i], hist[i]);
    __syncthreads();
    for (int i = tid; i < NBK; i += PTHREADS) hist[i] = scanb[i];  // staging cursor
    __syncthreads();

    #pragma unroll
    for (int e = 0; e < TILE / PTHREADS; ++e) {
        if (pb[e] >= 0) {
            int r = atomicAdd(&hist[pb[e]], 1);
            stage[r] = pv[e];
            bstage[r] = (unsigned short)pb[e];
        }
    }
    __syncthreads();

    // contiguous runs per bucket
    for (int i = tid; i < n; i += PTHREADS) {
        int b = bstage[i];
        bp[gbase[b] + (i - scanb[b])] = stage[i];
    }
}

// ---------------- per-bucket node degrees -> dinv ----------------
__global__ void nodedeg_k(const int* __restrict__ bp, const int* __restrict__ bcur,
                          float* __restrict__ dinv, int N) {
    __shared__ int cnt[GBKT];
    int k = blockIdx.x;
    int tid = threadIdx.x;
    int ebeg = k * CAP;
    int eend = bcur[k];
    if (tid < GBKT) cnt[tid] = 0;
    __syncthreads();
    for (int i = ebeg + tid; i < eend; i += 256)
        atomicAdd(&cnt[bp[i] & (GBKT - 1)], 1);
    __syncthreads();
    if (tid < GBKT) {
        int node = (k << BSH) + tid;
        if (node < N) dinv[node] = rsqrtf((float)(1 + cnt[tid]));
    }
}

// ---------------- y = bf16( (z @ W^T) * dinv[n] ), 32 rows/block ----------------
__global__ __launch_bounds__(512) void gemm_k(const float* __restrict__ z,
                                              const float* __restrict__ W,
                                              const float* __restrict__ dinv,
                                              ushort4* __restrict__ ybf, int N) {
    __shared__ float Wt[64 * 68];
    __shared__ float zt[32 * 68];
    int tid = threadIdx.x;
    for (int i = tid; i < DD * DD; i += 512) {
        int d = i >> 6, k = i & 63;
        Wt[k * 68 + d] = W[i];
    }
    {
        int zr = blockIdx.x * 32 + (tid >> 4);
        float4 v = (zr < N) ? reinterpret_cast<const float4*>(z)[(size_t)zr * 16 + (tid & 15)]
                            : make_float4(0.f, 0.f, 0.f, 0.f);
        *reinterpret_cast<float4*>(&zt[(tid >> 4) * 68 + (tid & 15) * 4]) = v;
    }
    __syncthreads();
    int r = tid >> 4;
    int c = tid & 15;
    int row = blockIdx.x * 32 + r;
    float4 acc = make_float4(0.f, 0.f, 0.f, 0.f);
    #pragma unroll
    for (int k = 0; k < DD; ++k) {
        float zv = zt[r * 68 + k];
        float4 w = *reinterpret_cast<const float4*>(&Wt[k * 68 + c * 4]);
        acc.x = fmaf(zv, w.x, acc.x);
        acc.y = fmaf(zv, w.y, acc.y);
        acc.z = fmaf(zv, w.z, acc.z);
        acc.w = fmaf(zv, w.w, acc.w);
    }
    if (row < N) {
        float s = dinv[row];
        ushort4 o;
        o.x = f2bf(acc.x * s);
        o.y = f2bf(acc.y * s);
        o.z = f2bf(acc.z * s);
        o.w = f2bf(acc.w * s);
        ybf[(size_t)row * 16 + c] = o;
    }
}

// ---------------- fused per-bucket LDS sort + gather + epilogue ----------------
// one block (512 thr, 8 waves) per 128-node bucket; 8-lane group per node slot,
// 8-deep load pipeline over prescaled bf16 rows.
// out[n] = relu( dinv[n] * ( y[n] + sum_s y[s] ) + b ),  y prescaled by dinv.
__global__ __launch_bounds__(512) void bg_k(const uint4* __restrict__ ybf,
                                            const int* __restrict__ bp,
                                            const int* __restrict__ bcur,
                                            const float4* __restrict__ b4,
                                            float4* __restrict__ out4, int N) {
    __shared__ int cnt[GBKT];
    __shared__ int excl[GBKT];
    __shared__ int cur[GBKT];
    __shared__ int sorted[CAP];   // 10 KB
    __shared__ int nextn;
    int k = blockIdx.x;
    int tid = threadIdx.x;
    int ebeg = k * CAP;
    int eend = bcur[k];
    int base = k << BSH;

    if (tid < GBKT) cnt[tid] = 0;
    if (tid == 0) nextn = 0;
    __syncthreads();
    for (int i = ebeg + tid; i < eend; i += 512)
        atomicAdd(&cnt[bp[i] & (GBKT - 1)], 1);
    __syncthreads();

    // 128-wide ladder scan (inclusive) -> exclusive
    if (tid < GBKT) excl[tid] = cnt[tid];
    __syncthreads();
    #pragma unroll
    for (int off = 1; off < GBKT; off <<= 1) {
        int t = (tid < GBKT && tid >= off) ? excl[tid - off] : 0;
        __syncthreads();
        if (tid < GBKT) excl[tid] += t;
        __syncthreads();
    }
    if (tid < GBKT) {
        excl[tid] -= cnt[tid];
        cur[tid] = excl[tid];
    }
    __syncthreads();

    // counting-sort fill into LDS
    for (int i = ebeg + tid; i < eend; i += 512) {
        int v = bp[i];
        int l = v & (GBKT - 1);
        int pos = atomicAdd(&cur[l], 1);
        sorted[pos] = v >> BSH;     // global src index
    }
    __syncthreads();

    // gather: 8-lane groups pull node slots dynamically
    int lane = tid & 63;
    int c = tid & 7;            // col block (8 bf16 cols = 16B)
    for (;;) {
        int slot;
        if ((tid & 7) == 0) slot = atomicAdd(&nextn, 1);
        slot = __shfl(slot, lane & 56, 64);
        if (slot >= GBKT) break;
        int node = base + slot;
        if (node >= N) continue;
        int beg = excl[slot];
        int cn = cnt[slot];
        int end = beg + cn;
        // self-loop message seeds accumulator set A
        uint4 v = ybf[(size_t)node * 8 + c];
        float4 a0 = make_float4(bflo(v.x), bfhi(v.x), bflo(v.y), bfhi(v.y));
        float4 a1 = make_float4(bflo(v.z), bfhi(v.z), bflo(v.w), bfhi(v.w));
        float4 e0 = make_float4(0.f, 0.f, 0.f, 0.f);
        float4 e1 = e0;
        int j = beg;
        for (; j + 7 < end; j += 8) {   // 8-deep pipeline
            int s0 = sorted[j],     s1 = sorted[j + 1], s2 = sorted[j + 2], s3 = sorted[j + 3];
            int s4 = sorted[j + 4], s5 = sorted[j + 5], s6 = sorted[j + 6], s7 = sorted[j + 7];
            uint4 r0 = ybf[(size_t)s0 * 8 + c];
            uint4 r1 = ybf[(size_t)s1 * 8 + c];
            uint4 r2 = ybf[(size_t)s2 * 8 + c];
            uint4 r3 = ybf[(size_t)s3 * 8 + c];
            uint4 r4 = ybf[(size_t)s4 * 8 + c];
            uint4 r5 = ybf[(size_t)s5 * 8 + c];
            uint4 r6 = ybf[(size_t)s6 * 8 + c];
            uint4 r7 = ybf[(size_t)s7 * 8 + c];
            acc_row(r0, a0, a1);
            acc_row(r1, e0, e1);
            acc_row(r2, a0, a1);
            acc_row(r3, e0, e1);
            acc_row(r4, a0, a1);
            acc_row(r5, e0, e1);
            acc_row(r6, a0, a1);
            acc_row(r7, e0, e1);
        }
        for (; j + 3 < end; j += 4) {
            int s0 = sorted[j], s1 = sorted[j + 1], s2 = sorted[j + 2], s3 = sorted[j + 3];
            uint4 r0 = ybf[(size_t)s0 * 8 + c];
            uint4 r1 = ybf[(size_t)s1 * 8 + c];
            uint4 r2 = ybf[(size_t)s2 * 8 + c];
            uint4 r3 = ybf[(size_t)s3 * 8 + c];
            acc_row(r0, a0, a1);
            acc_row(r1, e0, e1);
            acc_row(r2, a0, a1);
            acc_row(r3, e0, e1);
        }
        for (; j < end; ++j) {
            uint4 r = ybf[(size_t)sorted[j] * 8 + c];
            acc_row(r, a0, a1);
        }
        a0.x += e0.x; a0.y += e0.y; a0.z += e0.z; a0.w += e0.w;
        a1.x += e1.x; a1.y += e1.y; a1.z += e1.z; a1.w += e1.w;

        float dn = rsqrtf((float)(1 + cn));
        float4 bb0 = b4[2 * c];
        float4 bb1 = b4[2 * c + 1];
        float4 o0, o1;
        o0.x = fmaxf(fmaf(a0.x, dn, bb0.x), 0.f);
        o0.y = fmaxf(fmaf(a0.y, dn, bb0.y), 0.f);
        o0.z = fmaxf(fmaf(a0.z, dn, bb0.z), 0.f);
        o0.w = fmaxf(fmaf(a0.w, dn, bb0.w), 0.f);
        o1.x = fmaxf(fmaf(a1.x, dn, bb1.x), 0.f);
        o1.y = fmaxf(fmaf(a1.y, dn, bb1.y), 0.f);
        o1.z = fmaxf(fmaf(a1.z, dn, bb1.z), 0.f);
        o1.w = fmaxf(fmaf(a1.w, dn, bb1.w), 0.f);
        out4[(size_t)node * 16 + 2 * c] = o0;
        out4[(size_t)node * 16 + 2 * c + 1] = o1;
    }
}

// ---------------- launch ----------------

extern "C" void kernel_launch(void* const* d_in, const int* in_sizes, int n_in,
                              void* d_out, int out_size, void* d_ws, size_t ws_size,
                              hipStream_t stream) {
    const float* z = (const float*)d_in[0];
    const int* ei  = (const int*)d_in[1];
    const float* W = (const float*)d_in[2];
    const float* b = (const float*)d_in[3];
    float* out = (float*)d_out;

    const int N = in_sizes[0] / DD;
    const int E = in_sizes[1] / 2;
    const int* src = ei;
    const int* dst = ei + E;

    const int NBK = (N + GBKT - 1) >> BSH;

    // workspace layout
    unsigned short* ybf = (unsigned short*)d_ws;      // 64N ushorts (bf16)
    float* dinv  = (float*)(ybf + (size_t)64 * N);    // N f
    int*   bcur  = (int*)(dinv + N);                  // NBK
    int*   bp    = bcur + NBK;                        // NBK*CAP

    init_k<<<(NBK + 255) / 256, 256, 0, stream>>>(bcur, NBK);
    part_k<<<(E + TILE - 1) / TILE, PTHREADS, 0, stream>>>(src, dst, bcur, bp, E, NBK);
    nodedeg_k<<<NBK, 256, 0, stream>>>(bp, bcur, dinv, N);
    gemm_k<<<(N + 31) / 32, 512, 0, stream>>>(z, W, dinv, (ushort4*)ybf, N);
    bg_k<<<NBK, 512, 0, stream>>>((const uint4*)ybf, bp, bcur,
                                  (const float4*)b, (float4*)out, N);
}

// Round 13
// 92.755 us; speedup vs baseline: 1.0498x; 1.0321x over previous
//
#include <hip/hip_runtime.h>

#define DD 64
#define BSH 7                   // 128 nodes per bucket
#define GBKT 128
#define CAP 2560                // edge capacity per bucket region (mean 2046, +11 sigma)
#define TILE 4096               // edges per partition block
#define PTHREADS 512            // part_k block size
#define MAXBK 1024              // part_k LDS arrays sized for NBK <= 1024
#define SRS 14                  // src sub-bucket shift (8 windows of 16384 nodes)

__device__ __forceinline__ float bflo(unsigned int u) {
    return __uint_as_float(u << 16);
}
__device__ __forceinline__ float bfhi(unsigned int u) {
    return __uint_as_float(u & 0xffff0000u);
}
__device__ __forceinline__ unsigned short f2bf(float f) {   // RNE
    unsigned int b = __float_as_uint(f);
    return (unsigned short)((b + 0x7fffu + ((b >> 16) & 1u)) >> 16);
}
__device__ __forceinline__ void acc_row(uint4 r, float4& lo, float4& hi) {
    lo.x += bflo(r.x); lo.y += bfhi(r.x);
    lo.z += bflo(r.y); lo.w += bfhi(r.y);
    hi.x += bflo(r.z); hi.y += bfhi(r.z);
    hi.z += bflo(r.w); hi.w += bfhi(r.w);
}

// ---------------- init per-bucket cursors to region bases ----------------
__global__ void init_k(int* __restrict__ bcur, int NBK) {
    int i = blockIdx.x * blockDim.x + threadIdx.x;
    if (i < NBK) bcur[i] = i * CAP;
}

// ---------------- bucketed partition into capacity-slotted regions ----------------
// packed = (src << BSH) | (dst & (GBKT-1))
__global__ __launch_bounds__(PTHREADS) void part_k(const int* __restrict__ src,
                                                   const int* __restrict__ dst,
                                                   int* __restrict__ bcur,
                                                   int* __restrict__ bp,
                                                   int E, int NBK) {
    __shared__ int hist[MAXBK];
    __shared__ int scanb[MAXBK];
    __shared__ int gbase[MAXBK];
    __shared__ int stage[TILE];             // 16 KB packed
    __shared__ unsigned short bstage[TILE]; // 8 KB bucket ids

    int tid = threadIdx.x;
    int tbase = blockIdx.x * TILE;
    int n = E - tbase;
    if (n > TILE) n = TILE;

    for (int i = tid; i < NBK; i += PTHREADS) hist[i] = 0;
    __syncthreads();

    int pv[TILE / PTHREADS];
    int pb[TILE / PTHREADS];
    #pragma unroll
    for (int e = 0; e < TILE / PTHREADS; ++e) {
        int i = tid + e * PTHREADS;
        pb[e] = -1;
        if (i < n) {
            int s = src[tbase + i];
            int d = dst[tbase + i];
            pv[e] = (s << BSH) | (d & (GBKT - 1));
            pb[e] = d >> BSH;
            atomicAdd(&hist[pb[e]], 1);
        }
    }
    __syncthreads();

    // one-wave chunked exclusive scan of hist -> scanb
    if (tid < 64) {
        int run = 0;
        for (int base = 0; base < NBK; base += 64) {
            int i = base + tid;
            int orig = (i < NBK) ? hist[i] : 0;
            int v = orig;
            #pragma unroll
            for (int off = 1; off < 64; off <<= 1) {
                int t = __shfl_up(v, off, 64);
                if (tid >= off) v += t;
            }
            if (i < NBK) scanb[i] = run + v - orig;
            run += __shfl(v, 63, 64);
        }
    }
    __syncthreads();

    // reserve ranges in each bucket's region
    for (int i = tid; i < NBK; i += PTHREADS)
        if (hist[i]) gbase[i] = atomicAdd(&bcur[i], hist[i]);
    __syncthreads();
    for (int i = tid; i < NBK; i += PTHREADS) hist[i] = scanb[i];  // staging cursor
    __syncthreads();

    #pragma unroll
    for (int e = 0; e < TILE / PTHREADS; ++e) {
        if (pb[e] >= 0) {
            int r = atomicAdd(&hist[pb[e]], 1);
            stage[r] = pv[e];
            bstage[r] = (unsigned short)pb[e];
        }
    }
    __syncthreads();

    // contiguous runs per bucket
    for (int i = tid; i < n; i += PTHREADS) {
        int b = bstage[i];
        bp[gbase[b] + (i - scanb[b])] = stage[i];
    }
}

// ---------------- per-bucket node degrees -> dinv ----------------
__global__ void nodedeg_k(const int* __restrict__ bp, const int* __restrict__ bcur,
                          float* __restrict__ dinv, int N) {
    __shared__ int cnt[GBKT];
    int k = blockIdx.x;
    int tid = threadIdx.x;
    int ebeg = k * CAP;
    int eend = bcur[k];
    if (tid < GBKT) cnt[tid] = 0;
    __syncthreads();
    for (int i = ebeg + tid; i < eend; i += 256)
        atomicAdd(&cnt[bp[i] & (GBKT - 1)], 1);
    __syncthreads();
    if (tid < GBKT) {
        int node = (k << BSH) + tid;
        if (node < N) dinv[node] = rsqrtf((float)(1 + cnt[tid]));
    }
}

// ---------------- y = bf16( (z @ W^T) * dinv[n] ), 32 rows/block ----------------
__global__ __launch_bounds__(512) void gemm_k(const float* __restrict__ z,
                                              const float* __restrict__ W,
                                              const float* __restrict__ dinv,
                                              ushort4* __restrict__ ybf, int N) {
    __shared__ float Wt[64 * 68];
    __shared__ float zt[32 * 68];
    int tid = threadIdx.x;
    for (int i = tid; i < DD * DD; i += 512) {
        int d = i >> 6, k = i & 63;
        Wt[k * 68 + d] = W[i];
    }
    {
        int zr = blockIdx.x * 32 + (tid >> 4);
        float4 v = (zr < N) ? reinterpret_cast<const float4*>(z)[(size_t)zr * 16 + (tid & 15)]
                            : make_float4(0.f, 0.f, 0.f, 0.f);
        *reinterpret_cast<float4*>(&zt[(tid >> 4) * 68 + (tid & 15) * 4]) = v;
    }
    __syncthreads();
    int r = tid >> 4;
    int c = tid & 15;
    int row = blockIdx.x * 32 + r;
    float4 acc = make_float4(0.f, 0.f, 0.f, 0.f);
    #pragma unroll
    for (int k = 0; k < DD; ++k) {
        float zv = zt[r * 68 + k];
        float4 w = *reinterpret_cast<const float4*>(&Wt[k * 68 + c * 4]);
        acc.x = fmaf(zv, w.x, acc.x);
        acc.y = fmaf(zv, w.y, acc.y);
        acc.z = fmaf(zv, w.z, acc.z);
        acc.w = fmaf(zv, w.w, acc.w);
    }
    if (row < N) {
        float s = dinv[row];
        ushort4 o;
        o.x = f2bf(acc.x * s);
        o.y = f2bf(acc.y * s);
        o.z = f2bf(acc.z * s);
        o.w = f2bf(acc.w * s);
        ybf[(size_t)row * 16 + c] = o;
    }
}

// ---------------- fused per-bucket LDS sort + gather + epilogue ----------------
// one block (256 thr) per 128-node bucket. Counting sort keys on
// (dst_local, src>>SRS): per-node contiguous lists in ASCENDING src windows,
// so concurrent groups sweep y space in phase -> L2-resident window.
__global__ __launch_bounds__(256) void bg_k(const uint4* __restrict__ ybf,
                                            const int* __restrict__ bp,
                                            const int* __restrict__ bcur,
                                            const float4* __restrict__ b4,
                                            float4* __restrict__ out4, int N) {
    __shared__ int cnt[GBKT];
    __shared__ int excl[GBKT];
    __shared__ int cur2[GBKT * 8];   // 4 KB: per (node, src-window) cursor
    __shared__ int sorted[CAP];      // 10 KB
    __shared__ int nextn;
    int k = blockIdx.x;
    int tid = threadIdx.x;
    int ebeg = k * CAP;
    int eend = bcur[k];
    int base = k << BSH;

    if (tid < GBKT) cnt[tid] = 0;
    for (int i = tid; i < GBKT * 8; i += 256) cur2[i] = 0;
    if (tid == 0) nextn = 0;
    __syncthreads();
    // histogram: per-node count + per-(node, src-window) count
    for (int i = ebeg + tid; i < eend; i += 256) {
        int v = bp[i];
        int l = v & (GBKT - 1);
        int h = (v >> BSH) >> SRS;      // 0..7 src window
        atomicAdd(&cnt[l], 1);
        atomicAdd(&cur2[l * 8 + h], 1);
    }
    __syncthreads();

    // 128-wide ladder scan of cnt -> excl (exclusive)
    if (tid < GBKT) excl[tid] = cnt[tid];
    __syncthreads();
    #pragma unroll
    for (int off = 1; off < GBKT; off <<= 1) {
        int t = (tid < GBKT && tid >= off) ? excl[tid - off] : 0;
        __syncthreads();
        if (tid < GBKT) excl[tid] += t;
        __syncthreads();
    }
    if (tid < GBKT) {
        excl[tid] -= cnt[tid];
        // serial scan of the node's 8 window counts -> cursors
        int run = excl[tid];
        #pragma unroll
        for (int h = 0; h < 8; ++h) {
            int c = cur2[tid * 8 + h];
            cur2[tid * 8 + h] = run;
            run += c;
        }
    }
    __syncthreads();

    // counting-sort fill into LDS: per-node lists, src-window ascending
    for (int i = ebeg + tid; i < eend; i += 256) {
        int v = bp[i];
        int l = v & (GBKT - 1);
        int s = v >> BSH;
        int pos = atomicAdd(&cur2[l * 8 + (s >> SRS)], 1);
        sorted[pos] = s;
    }
    __syncthreads();

    // gather: 8-lane groups pull node slots dynamically
    int lane = tid & 63;
    int c = tid & 7;            // col block (8 bf16 cols = 16B)
    for (;;) {
        int slot;
        if ((tid & 7) == 0) slot = atomicAdd(&nextn, 1);
        slot = __shfl(slot, lane & 56, 64);
        if (slot >= GBKT) break;
        int node = base + slot;
        if (node >= N) continue;
        int beg = excl[slot];
        int cn = cnt[slot];
        int end = beg + cn;
        // self-loop message seeds accumulator set A
        uint4 v = ybf[(size_t)node * 8 + c];
        float4 a0 = make_float4(bflo(v.x), bfhi(v.x), bflo(v.y), bfhi(v.y));
        float4 a1 = make_float4(bflo(v.z), bfhi(v.z), bflo(v.w), bfhi(v.w));
        float4 e0 = make_float4(0.f, 0.f, 0.f, 0.f);
        float4 e1 = e0;
        int j = beg;
        for (; j + 7 < end; j += 8) {   // 8-deep pipeline
            int s0 = sorted[j],     s1 = sorted[j + 1], s2 = sorted[j + 2], s3 = sorted[j + 3];
            int s4 = sorted[j + 4], s5 = sorted[j + 5], s6 = sorted[j + 6], s7 = sorted[j + 7];
            uint4 r0 = ybf[(size_t)s0 * 8 + c];
            uint4 r1 = ybf[(size_t)s1 * 8 + c];
            uint4 r2 = ybf[(size_t)s2 * 8 + c];
            uint4 r3 = ybf[(size_t)s3 * 8 + c];
            uint4 r4 = ybf[(size_t)s4 * 8 + c];
            uint4 r5 = ybf[(size_t)s5 * 8 + c];
            uint4 r6 = ybf[(size_t)s6 * 8 + c];
            uint4 r7 = ybf[(size_t)s7 * 8 + c];
            acc_row(r0, a0, a1);
            acc_row(r1, e0, e1);
            acc_row(r2, a0, a1);
            acc_row(r3, e0, e1);
            acc_row(r4, a0, a1);
            acc_row(r5, e0, e1);
            acc_row(r6, a0, a1);
            acc_row(r7, e0, e1);
        }
        for (; j + 3 < end; j += 4) {
            int s0 = sorted[j], s1 = sorted[j + 1], s2 = sorted[j + 2], s3 = sorted[j + 3];
            uint4 r0 = ybf[(size_t)s0 * 8 + c];
            uint4 r1 = ybf[(size_t)s1 * 8 + c];
            uint4 r2 = ybf[(size_t)s2 * 8 + c];
            uint4 r3 = ybf[(size_t)s3 * 8 + c];
            acc_row(r0, a0, a1);
            acc_row(r1, e0, e1);
            acc_row(r2, a0, a1);
            acc_row(r3, e0, e1);
        }
        for (; j < end; ++j) {
            uint4 r = ybf[(size_t)sorted[j] * 8 + c];
            acc_row(r, a0, a1);
        }
        a0.x += e0.x; a0.y += e0.y; a0.z += e0.z; a0.w += e0.w;
        a1.x += e1.x; a1.y += e1.y; a1.z += e1.z; a1.w += e1.w;

        float dn = rsqrtf((float)(1 + cn));
        float4 bb0 = b4[2 * c];
        float4 bb1 = b4[2 * c + 1];
        float4 o0, o1;
        o0.x = fmaxf(fmaf(a0.x, dn, bb0.x), 0.f);
        o0.y = fmaxf(fmaf(a0.y, dn, bb0.y), 0.f);
        o0.z = fmaxf(fmaf(a0.z, dn, bb0.z), 0.f);
        o0.w = fmaxf(fmaf(a0.w, dn, bb0.w), 0.f);
        o1.x = fmaxf(fmaf(a1.x, dn, bb1.x), 0.f);
        o1.y = fmaxf(fmaf(a1.y, dn, bb1.y), 0.f);
        o1.z = fmaxf(fmaf(a1.z, dn, bb1.z), 0.f);
        o1.w = fmaxf(fmaf(a1.w, dn, bb1.w), 0.f);
        out4[(size_t)node * 16 + 2 * c] = o0;
        out4[(size_t)node * 16 + 2 * c + 1] = o1;
    }
}

// ---------------- launch ----------------

extern "C" void kernel_launch(void* const* d_in, const int* in_sizes, int n_in,
                              void* d_out, int out_size, void* d_ws, size_t ws_size,
                              hipStream_t stream) {
    const float* z = (const float*)d_in[0];
    const int* ei  = (const int*)d_in[1];
    const float* W = (const float*)d_in[2];
    const float* b = (const float*)d_in[3];
    float* out = (float*)d_out;

    const int N = in_sizes[0] / DD;
    const int E = in_sizes[1] / 2;
    const int* src = ei;
    const int* dst = ei + E;

    const int NBK = (N + GBKT - 1) >> BSH;

    // workspace layout
    unsigned short* ybf = (unsigned short*)d_ws;      // 64N ushorts (bf16)
    float* dinv  = (float*)(ybf + (size_t)64 * N);    // N f
    int*   bcur  = (int*)(dinv + N);                  // NBK
    int*   bp    = bcur + NBK;                        // NBK*CAP

    init_k<<<(NBK + 255) / 256, 256, 0, stream>>>(bcur, NBK);
    part_k<<<(E + TILE - 1) / TILE, PTHREADS, 0, stream>>>(src, dst, bcur, bp, E, NBK);
    nodedeg_k<<<NBK, 256, 0, stream>>>(bp, bcur, dinv, N);
    gemm_k<<<(N + 31) / 32, 512, 0, stream>>>(z, W, dinv, (ushort4*)ybf, N);
    bg_k<<<NBK, 256, 0, stream>>>((const uint4*)ybf, bp, bcur,
                                  (const float4*)b, (float4*)out, N);
}

// Round 15
// 92.302 us; speedup vs baseline: 1.0550x; 1.0049x over previous
//
#include <hip/hip_runtime.h>

#define DD 64
#define BSH 7                   // 128 nodes per bucket
#define GBKT 128
#define CAP 2560                // = 10*256; mean fill 2046, +11 sigma
#define TILE 4096               // edges per partition tile
#define PTHREADS 512
#define EPT 8                   // TILE/PTHREADS
#define MAXBK 1024              // >= NBK

__device__ __forceinline__ float bflo(unsigned int u) {
    return __uint_as_float(u << 16);
}
__device__ __forceinline__ float bfhi(unsigned int u) {
    return __uint_as_float(u & 0xffff0000u);
}
__device__ __forceinline__ unsigned short f2bf(float f) {   // RNE
    unsigned int b = __float_as_uint(f);
    return (unsigned short)((b + 0x7fffu + ((b >> 16) & 1u)) >> 16);
}
__device__ __forceinline__ void acc_row(uint4 r, float4& lo, float4& hi) {
    lo.x += bflo(r.x); lo.y += bfhi(r.x);
    lo.z += bflo(r.y); lo.w += bfhi(r.y);
    hi.x += bflo(r.z); hi.y += bfhi(r.z);
    hi.z += bflo(r.w); hi.w += bfhi(r.w);
}

// ---------------- bucketed partition; bcur holds per-bucket COUNTS (memset 0) ----------------
// packed = (src << BSH) | (dst & (GBKT-1))
__global__ __launch_bounds__(PTHREADS) void part_k(const int* __restrict__ src,
                                                   const int* __restrict__ dst,
                                                   int* __restrict__ bcur,
                                                   int* __restrict__ bp,
                                                   int E, int NBK) {
    __shared__ int hist[MAXBK];
    __shared__ int scanb[MAXBK];
    __shared__ int gbase[MAXBK];
    __shared__ int stage[TILE];             // 16 KB packed
    __shared__ unsigned short bstage[TILE]; // 8 KB bucket ids

    int tid = threadIdx.x;
    int tbase = blockIdx.x * TILE;
    int n = E - tbase;
    if (n > TILE) n = TILE;

    for (int i = tid; i < NBK; i += PTHREADS) hist[i] = 0;
    __syncthreads();

    // load 8 consecutive edges per thread (int4 x2 when aligned & full)
    int ss[EPT], dd[EPT];
    int eb = tid * EPT;                     // within tile
    bool dal = ((reinterpret_cast<size_t>(dst) & 15) == 0);
    if (dal && eb + EPT <= n) {
        const int4* s4 = (const int4*)(src + tbase + eb);
        const int4* d4 = (const int4*)(dst + tbase + eb);
        int4 a = s4[0], b2 = s4[1], c4 = d4[0], e4 = d4[1];
        ss[0] = a.x; ss[1] = a.y; ss[2] = a.z; ss[3] = a.w;
        ss[4] = b2.x; ss[5] = b2.y; ss[6] = b2.z; ss[7] = b2.w;
        dd[0] = c4.x; dd[1] = c4.y; dd[2] = c4.z; dd[3] = c4.w;
        dd[4] = e4.x; dd[5] = e4.y; dd[6] = e4.z; dd[7] = e4.w;
    } else {
        #pragma unroll
        for (int e = 0; e < EPT; ++e) {
            if (eb + e < n) { ss[e] = src[tbase + eb + e]; dd[e] = dst[tbase + eb + e]; }
            else dd[e] = -1;
        }
    }
    // single atomic pass: rank within (tile, bucket)
    int pv[EPT], pb[EPT], pr[EPT];
    #pragma unroll
    for (int e = 0; e < EPT; ++e) {
        pb[e] = -1;
        if (eb + e < n && dd[e] >= 0) {
            pv[e] = (ss[e] << BSH) | (dd[e] & (GBKT - 1));
            pb[e] = dd[e] >> BSH;
            pr[e] = atomicAdd(&hist[pb[e]], 1);
        }
    }
    __syncthreads();

    // one-wave chunked exclusive scan of hist -> scanb
    if (tid < 64) {
        int run = 0;
        for (int base = 0; base < NBK; base += 64) {
            int i = base + tid;
            int orig = (i < NBK) ? hist[i] : 0;
            int v = orig;
            #pragma unroll
            for (int off = 1; off < 64; off <<= 1) {
                int t = __shfl_up(v, off, 64);
                if (tid >= off) v += t;
            }
            if (i < NBK) scanb[i] = run + v - orig;
            run += __shfl(v, 63, 64);
        }
    }
    __syncthreads();

    // reserve global ranges (bcur = counts) and place staged edges
    for (int i = tid; i < NBK; i += PTHREADS)
        if (hist[i]) gbase[i] = i * CAP + atomicAdd(&bcur[i], hist[i]);
    #pragma unroll
    for (int e = 0; e < EPT; ++e) {
        if (pb[e] >= 0) {
            int p = scanb[pb[e]] + pr[e];
            stage[p] = pv[e];
            bstage[p] = (unsigned short)pb[e];
        }
    }
    __syncthreads();

    // contiguous runs per bucket
    for (int i = tid; i < n; i += PTHREADS) {
        int b = bstage[i];
        bp[gbase[b] + (i - scanb[b])] = stage[i];
    }
}

// ---------------- per-bucket node degrees -> dinv ----------------
__global__ void nodedeg_k(const int* __restrict__ bp, const int* __restrict__ bcur,
                          float* __restrict__ dinv, int N) {
    __shared__ int cnt[GBKT];
    int k = blockIdx.x;
    int tid = threadIdx.x;
    int ebeg = k * CAP;
    int eend = ebeg + bcur[k];
    if (tid < GBKT) cnt[tid] = 0;
    __syncthreads();
    for (int i = ebeg + tid; i < eend; i += 256)
        atomicAdd(&cnt[bp[i] & (GBKT - 1)], 1);
    __syncthreads();
    if (tid < GBKT) {
        int node = (k << BSH) + tid;
        if (node < N) dinv[node] = rsqrtf((float)(1 + cnt[tid]));
    }
}

// ---------------- y = bf16( (z @ W^T) * dinv[n] ), 32 rows/block ----------------
__global__ __launch_bounds__(512) void gemm_k(const float* __restrict__ z,
                                              const float* __restrict__ W,
                                              const float* __restrict__ dinv,
                                              ushort4* __restrict__ ybf, int N) {
    __shared__ float Wt[64 * 68];
    __shared__ float zt[32 * 68];
    int tid = threadIdx.x;
    for (int i = tid; i < DD * DD; i += 512) {
        int d = i >> 6, k = i & 63;
        Wt[k * 68 + d] = W[i];
    }
    {
        int zr = blockIdx.x * 32 + (tid >> 4);
        float4 v = (zr < N) ? reinterpret_cast<const float4*>(z)[(size_t)zr * 16 + (tid & 15)]
                            : make_float4(0.f, 0.f, 0.f, 0.f);
        *reinterpret_cast<float4*>(&zt[(tid >> 4) * 68 + (tid & 15) * 4]) = v;
    }
    __syncthreads();
    int r = tid >> 4;
    int c = tid & 15;
    int row = blockIdx.x * 32 + r;
    float4 acc = make_float4(0.f, 0.f, 0.f, 0.f);
    #pragma unroll
    for (int k = 0; k < DD; ++k) {
        float zv = zt[r * 68 + k];
        float4 w = *reinterpret_cast<const float4*>(&Wt[k * 68 + c * 4]);
        acc.x = fmaf(zv, w.x, acc.x);
        acc.y = fmaf(zv, w.y, acc.y);
        acc.z = fmaf(zv, w.z, acc.z);
        acc.w = fmaf(zv, w.w, acc.w);
    }
    if (row < N) {
        float s = dinv[row];
        ushort4 o;
        o.x = f2bf(acc.x * s);
        o.y = f2bf(acc.y * s);
        o.z = f2bf(acc.z * s);
        o.w = f2bf(acc.w * s);
        ybf[(size_t)row * 16 + c] = o;
    }
}

// ---------------- fused per-bucket sort (single reg-cached bp pass) + gather ----------------
__global__ __launch_bounds__(256) void bg_k(const uint4* __restrict__ ybf,
                                            const int* __restrict__ bp,
                                            const int* __restrict__ bcur,
                                            const float4* __restrict__ b4,
                                            float4* __restrict__ out4, int N) {
    __shared__ int cnt[GBKT];
    __shared__ int excl[GBKT];
    __shared__ int cur[GBKT];
    __shared__ int sorted[CAP];   // 10 KB
    __shared__ int nextn;
    int k = blockIdx.x;
    int tid = threadIdx.x;
    int ebeg = k * CAP;
    int eend = ebeg + bcur[k];
    int base = k << BSH;

    if (tid < GBKT) cnt[tid] = 0;
    if (tid == 0) nextn = 0;
    __syncthreads();
    // single bp read, cached in registers (CAP == 10*256)
    int ev[10];
    #pragma unroll
    for (int u = 0; u < 10; ++u) {
        int i = ebeg + tid + u * 256;
        ev[u] = (i < eend) ? bp[i] : -1;
    }
    #pragma unroll
    for (int u = 0; u < 10; ++u)
        if (ev[u] >= 0) atomicAdd(&cnt[ev[u] & (GBKT - 1)], 1);
    __syncthreads();

    // 128-wide ladder scan (inclusive) -> exclusive
    if (tid < GBKT) excl[tid] = cnt[tid];
    __syncthreads();
    #pragma unroll
    for (int off = 1; off < GBKT; off <<= 1) {
        int t = (tid < GBKT && tid >= off) ? excl[tid - off] : 0;
        __syncthreads();
        if (tid < GBKT) excl[tid] += t;
        __syncthreads();
    }
    if (tid < GBKT) {
        excl[tid] -= cnt[tid];
        cur[tid] = excl[tid];
    }
    __syncthreads();

    #pragma unroll
    for (int u = 0; u < 10; ++u)
        if (ev[u] >= 0) {
            int l = ev[u] & (GBKT - 1);
            int pos = atomicAdd(&cur[l], 1);
            sorted[pos] = ev[u] >> BSH;
        }
    __syncthreads();

    // gather: 8-lane groups pull node slots dynamically
    int lane = tid & 63;
    int c = tid & 7;            // col block (8 bf16 cols = 16B)
    for (;;) {
        int slot;
        if ((tid & 7) == 0) slot = atomicAdd(&nextn, 1);
        slot = __shfl(slot, lane & 56, 64);
        if (slot >= GBKT) break;
        int node = base + slot;
        if (node >= N) continue;
        int beg = excl[slot];
        int cn = cnt[slot];
        int end = beg + cn;
        // self-loop message seeds accumulator set A
        uint4 v = ybf[(size_t)node * 8 + c];
        float4 a0 = make_float4(bflo(v.x), bfhi(v.x), bflo(v.y), bfhi(v.y));
        float4 a1 = make_float4(bflo(v.z), bfhi(v.z), bflo(v.w), bfhi(v.w));
        float4 e0 = make_float4(0.f, 0.f, 0.f, 0.f);
        float4 e1 = e0;
        int j = beg;
        for (; j + 7 < end; j += 8) {   // 8-deep pipeline
            int s0 = sorted[j],     s1 = sorted[j + 1], s2 = sorted[j + 2], s3 = sorted[j + 3];
            int s4 = sorted[j + 4], s5 = sorted[j + 5], s6 = sorted[j + 6], s7 = sorted[j + 7];
            uint4 r0 = ybf[(size_t)s0 * 8 + c];
            uint4 r1 = ybf[(size_t)s1 * 8 + c];
            uint4 r2 = ybf[(size_t)s2 * 8 + c];
            uint4 r3 = ybf[(size_t)s3 * 8 + c];
            uint4 r4 = ybf[(size_t)s4 * 8 + c];
            uint4 r5 = ybf[(size_t)s5 * 8 + c];
            uint4 r6 = ybf[(size_t)s6 * 8 + c];
            uint4 r7 = ybf[(size_t)s7 * 8 + c];
            acc_row(r0, a0, a1);
            acc_row(r1, e0, e1);
            acc_row(r2, a0, a1);
            acc_row(r3, e0, e1);
            acc_row(r4, a0, a1);
            acc_row(r5, e0, e1);
            acc_row(r6, a0, a1);
            acc_row(r7, e0, e1);
        }
        for (; j + 3 < end; j += 4) {
            int s0 = sorted[j], s1 = sorted[j + 1], s2 = sorted[j + 2], s3 = sorted[j + 3];
            uint4 r0 = ybf[(size_t)s0 * 8 + c];
            uint4 r1 = ybf[(size_t)s1 * 8 + c];
            uint4 r2 = ybf[(size_t)s2 * 8 + c];
            uint4 r3 = ybf[(size_t)s3 * 8 + c];
            acc_row(r0, a0, a1);
            acc_row(r1, e0, e1);
            acc_row(r2, a0, a1);
            acc_row(r3, e0, e1);
        }
        for (; j < end; ++j) {
            uint4 r = ybf[(size_t)sorted[j] * 8 + c];
            acc_row(r, a0, a1);
        }
        a0.x += e0.x; a0.y += e0.y; a0.z += e0.z; a0.w += e0.w;
        a1.x += e1.x; a1.y += e1.y; a1.z += e1.z; a1.w += e1.w;

        float dn = rsqrtf((float)(1 + cn));
        float4 bb0 = b4[2 * c];
        float4 bb1 = b4[2 * c + 1];
        float4 o0, o1;
        o0.x = fmaxf(fmaf(a0.x, dn, bb0.x), 0.f);
        o0.y = fmaxf(fmaf(a0.y, dn, bb0.y), 0.f);
        o0.z = fmaxf(fmaf(a0.z, dn, bb0.z), 0.f);
        o0.w = fmaxf(fmaf(a0.w, dn, bb0.w), 0.f);
        o1.x = fmaxf(fmaf(a1.x, dn, bb1.x), 0.f);
        o1.y = fmaxf(fmaf(a1.y, dn, bb1.y), 0.f);
        o1.z = fmaxf(fmaf(a1.z, dn, bb1.z), 0.f);
        o1.w = fmaxf(fmaf(a1.w, dn, bb1.w), 0.f);
        out4[(size_t)node * 16 + 2 * c] = o0;
        out4[(size_t)node * 16 + 2 * c + 1] = o1;
    }
}

// ---------------- launch ----------------

extern "C" void kernel_launch(void* const* d_in, const int* in_sizes, int n_in,
                              void* d_out, int out_size, void* d_ws, size_t ws_size,
                              hipStream_t stream) {
    const float* z = (const float*)d_in[0];
    const int* ei  = (const int*)d_in[1];
    const float* W = (const float*)d_in[2];
    const float* b = (const float*)d_in[3];
    float* out = (float*)d_out;

    const int N = in_sizes[0] / DD;
    const int E = in_sizes[1] / 2;
    const int* src = ei;
    const int* dst = ei + E;

    const int NBK = (N + GBKT - 1) >> BSH;

    // workspace layout
    unsigned short* ybf = (unsigned short*)d_ws;      // 64N ushorts (bf16)
    float* dinv  = (float*)(ybf + (size_t)64 * N);    // N f
    int*   bcur  = (int*)(dinv + N);                  // NBK (counts)
    int*   bp    = bcur + NBK;                        // NBK*CAP

    hipMemsetAsync(bcur, 0, sizeof(int) * NBK, stream);
    part_k<<<(E + TILE - 1) / TILE, PTHREADS, 0, stream>>>(src, dst, bcur, bp, E, NBK);
    nodedeg_k<<<NBK, 256, 0, stream>>>(bp, bcur, dinv, N);
    gemm_k<<<(N + 31) / 32, 512, 0, stream>>>(z, W, dinv, (ushort4*)ybf, N);
    bg_k<<<NBK, 256, 0, stream>>>((const uint4*)ybf, bp, bcur,
                                  (const float4*)b, (float4*)out, N);
}

// Round 16
// 87.707 us; speedup vs baseline: 1.1102x; 1.0524x over previous
//
#include <hip/hip_runtime.h>

#define DD 64
#define BSH 7                   // 128 nodes per bucket
#define GBKT 128
#define CAP 2560                // = 10*256; mean fill 2046, +11 sigma
#define TILE 8192               // edges per partition tile
#define PTHREADS 1024
#define EPT 8                   // TILE/PTHREADS
#define MAXBK 1024              // >= NBK

__device__ __forceinline__ float bflo(unsigned int u) {
    return __uint_as_float(u << 16);
}
__device__ __forceinline__ float bfhi(unsigned int u) {
    return __uint_as_float(u & 0xffff0000u);
}
__device__ __forceinline__ unsigned short f2bf(float f) {   // RNE
    unsigned int b = __float_as_uint(f);
    return (unsigned short)((b + 0x7fffu + ((b >> 16) & 1u)) >> 16);
}
__device__ __forceinline__ void acc_row(uint4 r, float4& lo, float4& hi) {
    lo.x += bflo(r.x); lo.y += bfhi(r.x);
    lo.z += bflo(r.y); lo.w += bfhi(r.y);
    hi.x += bflo(r.z); hi.y += bfhi(r.z);
    hi.z += bflo(r.w); hi.w += bfhi(r.w);
}

// ---------------- bucketed partition; bcur holds per-bucket COUNTS (memset 0) ----------------
// packed = (src << BSH) | (dst & (GBKT-1))
__global__ __launch_bounds__(PTHREADS) void part_k(const int* __restrict__ src,
                                                   const int* __restrict__ dst,
                                                   int* __restrict__ bcur,
                                                   int* __restrict__ bp,
                                                   int E, int NBK) {
    __shared__ int hist[MAXBK];
    __shared__ int scanb[MAXBK];
    __shared__ int gbase[MAXBK];
    __shared__ int stage[TILE];             // 32 KB packed
    __shared__ unsigned short bstage[TILE]; // 16 KB bucket ids

    int tid = threadIdx.x;
    int tbase = blockIdx.x * TILE;
    int n = E - tbase;
    if (n > TILE) n = TILE;

    for (int i = tid; i < NBK; i += PTHREADS) hist[i] = 0;
    __syncthreads();

    // 8 consecutive edges per thread (int4 x2 when aligned & full)
    int ss[EPT], dd[EPT];
    int eb = tid * EPT;                     // within tile
    bool dal = ((reinterpret_cast<size_t>(dst) & 15) == 0);
    if (dal && eb + EPT <= n) {
        const int4* s4 = (const int4*)(src + tbase + eb);
        const int4* d4 = (const int4*)(dst + tbase + eb);
        int4 a = s4[0], b2 = s4[1], c4 = d4[0], e4 = d4[1];
        ss[0] = a.x; ss[1] = a.y; ss[2] = a.z; ss[3] = a.w;
        ss[4] = b2.x; ss[5] = b2.y; ss[6] = b2.z; ss[7] = b2.w;
        dd[0] = c4.x; dd[1] = c4.y; dd[2] = c4.z; dd[3] = c4.w;
        dd[4] = e4.x; dd[5] = e4.y; dd[6] = e4.z; dd[7] = e4.w;
    } else {
        #pragma unroll
        for (int e = 0; e < EPT; ++e) {
            if (eb + e < n) { ss[e] = src[tbase + eb + e]; dd[e] = dst[tbase + eb + e]; }
            else dd[e] = -1;
        }
    }
    // single atomic pass: rank within (tile, bucket)
    int pv[EPT], pb[EPT], pr[EPT];
    #pragma unroll
    for (int e = 0; e < EPT; ++e) {
        pb[e] = -1;
        if (eb + e < n && dd[e] >= 0) {
            pv[e] = (ss[e] << BSH) | (dd[e] & (GBKT - 1));
            pb[e] = dd[e] >> BSH;
            pr[e] = atomicAdd(&hist[pb[e]], 1);
        }
    }
    __syncthreads();

    // one-wave chunked exclusive scan of hist -> scanb
    if (tid < 64) {
        int run = 0;
        for (int base = 0; base < NBK; base += 64) {
            int i = base + tid;
            int orig = (i < NBK) ? hist[i] : 0;
            int v = orig;
            #pragma unroll
            for (int off = 1; off < 64; off <<= 1) {
                int t = __shfl_up(v, off, 64);
                if (tid >= off) v += t;
            }
            if (i < NBK) scanb[i] = run + v - orig;
            run += __shfl(v, 63, 64);
        }
    }
    __syncthreads();

    // reserve global ranges (bcur = counts) and place staged edges
    for (int i = tid; i < NBK; i += PTHREADS)
        if (hist[i]) gbase[i] = i * CAP + atomicAdd(&bcur[i], hist[i]);
    #pragma unroll
    for (int e = 0; e < EPT; ++e) {
        if (pb[e] >= 0) {
            int p = scanb[pb[e]] + pr[e];
            stage[p] = pv[e];
            bstage[p] = (unsigned short)pb[e];
        }
    }
    __syncthreads();

    // contiguous runs per bucket
    for (int i = tid; i < n; i += PTHREADS) {
        int b = bstage[i];
        bp[gbase[b] + (i - scanb[b])] = stage[i];
    }
}

// ---------------- fused per-bucket degree + gemm: y = bf16((z @ W^T) * dinv) ----------------
// one block (512 thr) per 128-node bucket; dinv never leaves the block.
__global__ __launch_bounds__(512) void dg_k(const int* __restrict__ bp,
                                            const int* __restrict__ bcur,
                                            const float* __restrict__ z,
                                            const float* __restrict__ W,
                                            ushort4* __restrict__ ybf, int N) {
    __shared__ float Wt[64 * 68];    // 17.4 KB
    __shared__ float zt[32 * 68];    // 8.7 KB
    __shared__ int cnt[GBKT];
    __shared__ float dinvL[GBKT];
    int k = blockIdx.x;
    int tid = threadIdx.x;
    int base = k << BSH;

    if (tid < GBKT) cnt[tid] = 0;
    // stage W^T (independent of histogram)
    for (int i = tid; i < DD * DD; i += 512) {
        int d = i >> 6, kk = i & 63;
        Wt[kk * 68 + d] = W[i];
    }
    __syncthreads();
    {
        int ebeg = k * CAP;
        int eend = ebeg + bcur[k];
        for (int i = ebeg + tid; i < eend; i += 512)
            atomicAdd(&cnt[bp[i] & (GBKT - 1)], 1);
    }
    __syncthreads();
    if (tid < GBKT) dinvL[tid] = rsqrtf((float)(1 + cnt[tid]));
    // 4 x 32-row gemm sub-tiles
    for (int it = 0; it < 4; ++it) {
        __syncthreads();   // dinvL ready (it==0) / previous zt consumed
        int rl = it * 32 + (tid >> 4);           // local row 0..127
        int row = base + rl;
        float4 v = (row < N) ? ((const float4*)z)[(size_t)row * 16 + (tid & 15)]
                             : make_float4(0.f, 0.f, 0.f, 0.f);
        *(float4*)&zt[(tid >> 4) * 68 + (tid & 15) * 4] = v;
        __syncthreads();
        int r = tid >> 4, c = tid & 15;
        float4 acc = make_float4(0.f, 0.f, 0.f, 0.f);
        #pragma unroll
        for (int kk = 0; kk < DD; ++kk) {
            float zv = zt[r * 68 + kk];
            float4 w = *(const float4*)&Wt[kk * 68 + c * 4];
            acc.x = fmaf(zv, w.x, acc.x);
            acc.y = fmaf(zv, w.y, acc.y);
            acc.z = fmaf(zv, w.z, acc.z);
            acc.w = fmaf(zv, w.w, acc.w);
        }
        if (row < N) {
            float s = dinvL[rl];
            ushort4 o;
            o.x = f2bf(acc.x * s);
            o.y = f2bf(acc.y * s);
            o.z = f2bf(acc.z * s);
            o.w = f2bf(acc.w * s);
            ybf[(size_t)row * 16 + c] = o;
        }
    }
}

// ---------------- fused per-bucket sort (single reg-cached bp pass) + gather ----------------
__global__ __launch_bounds__(256) void bg_k(const uint4* __restrict__ ybf,
                                            const int* __restrict__ bp,
                                            const int* __restrict__ bcur,
                                            const float4* __restrict__ b4,
                                            float4* __restrict__ out4, int N) {
    __shared__ int cnt[GBKT];
    __shared__ int excl[GBKT];
    __shared__ int cur[GBKT];
    __shared__ int sorted[CAP];   // 10 KB
    __shared__ int nextn;
    int k = blockIdx.x;
    int tid = threadIdx.x;
    int ebeg = k * CAP;
    int eend = ebeg + bcur[k];
    int base = k << BSH;

    if (tid < GBKT) cnt[tid] = 0;
    if (tid == 0) nextn = 0;
    __syncthreads();
    // single bp read, cached in registers (CAP == 10*256)
    int ev[10];
    #pragma unroll
    for (int u = 0; u < 10; ++u) {
        int i = ebeg + tid + u * 256;
        ev[u] = (i < eend) ? bp[i] : -1;
    }
    #pragma unroll
    for (int u = 0; u < 10; ++u)
        if (ev[u] >= 0) atomicAdd(&cnt[ev[u] & (GBKT - 1)], 1);
    __syncthreads();

    // 128-wide ladder scan (inclusive) -> exclusive
    if (tid < GBKT) excl[tid] = cnt[tid];
    __syncthreads();
    #pragma unroll
    for (int off = 1; off < GBKT; off <<= 1) {
        int t = (tid < GBKT && tid >= off) ? excl[tid - off] : 0;
        __syncthreads();
        if (tid < GBKT) excl[tid] += t;
        __syncthreads();
    }
    if (tid < GBKT) {
        excl[tid] -= cnt[tid];
        cur[tid] = excl[tid];
    }
    __syncthreads();

    #pragma unroll
    for (int u = 0; u < 10; ++u)
        if (ev[u] >= 0) {
            int l = ev[u] & (GBKT - 1);
            int pos = atomicAdd(&cur[l], 1);
            sorted[pos] = ev[u] >> BSH;
        }
    __syncthreads();

    // gather: 8-lane groups pull node slots dynamically
    int lane = tid & 63;
    int c = tid & 7;            // col block (8 bf16 cols = 16B)
    for (;;) {
        int slot;
        if ((tid & 7) == 0) slot = atomicAdd(&nextn, 1);
        slot = __shfl(slot, lane & 56, 64);
        if (slot >= GBKT) break;
        int node = base + slot;
        if (node >= N) continue;
        int beg = excl[slot];
        int cn = cnt[slot];
        int end = beg + cn;
        // self-loop message seeds accumulator set A
        uint4 v = ybf[(size_t)node * 8 + c];
        float4 a0 = make_float4(bflo(v.x), bfhi(v.x), bflo(v.y), bfhi(v.y));
        float4 a1 = make_float4(bflo(v.z), bfhi(v.z), bflo(v.w), bfhi(v.w));
        float4 e0 = make_float4(0.f, 0.f, 0.f, 0.f);
        float4 e1 = e0;
        int j = beg;
        for (; j + 7 < end; j += 8) {   // 8-deep pipeline
            int s0 = sorted[j],     s1 = sorted[j + 1], s2 = sorted[j + 2], s3 = sorted[j + 3];
            int s4 = sorted[j + 4], s5 = sorted[j + 5], s6 = sorted[j + 6], s7 = sorted[j + 7];
            uint4 r0 = ybf[(size_t)s0 * 8 + c];
            uint4 r1 = ybf[(size_t)s1 * 8 + c];
            uint4 r2 = ybf[(size_t)s2 * 8 + c];
            uint4 r3 = ybf[(size_t)s3 * 8 + c];
            uint4 r4 = ybf[(size_t)s4 * 8 + c];
            uint4 r5 = ybf[(size_t)s5 * 8 + c];
            uint4 r6 = ybf[(size_t)s6 * 8 + c];
            uint4 r7 = ybf[(size_t)s7 * 8 + c];
            acc_row(r0, a0, a1);
            acc_row(r1, e0, e1);
            acc_row(r2, a0, a1);
            acc_row(r3, e0, e1);
            acc_row(r4, a0, a1);
            acc_row(r5, e0, e1);
            acc_row(r6, a0, a1);
            acc_row(r7, e0, e1);
        }
        for (; j + 3 < end; j += 4) {
            int s0 = sorted[j], s1 = sorted[j + 1], s2 = sorted[j + 2], s3 = sorted[j + 3];
            uint4 r0 = ybf[(size_t)s0 * 8 + c];
            uint4 r1 = ybf[(size_t)s1 * 8 + c];
            uint4 r2 = ybf[(size_t)s2 * 8 + c];
            uint4 r3 = ybf[(size_t)s3 * 8 + c];
            acc_row(r0, a0, a1);
            acc_row(r1, e0, e1);
            acc_row(r2, a0, a1);
            acc_row(r3, e0, e1);
        }
        for (; j < end; ++j) {
            uint4 r = ybf[(size_t)sorted[j] * 8 + c];
            acc_row(r, a0, a1);
        }
        a0.x += e0.x; a0.y += e0.y; a0.z += e0.z; a0.w += e0.w;
        a1.x += e1.x; a1.y += e1.y; a1.z += e1.z; a1.w += e1.w;

        float dn = rsqrtf((float)(1 + cn));
        float4 bb0 = b4[2 * c];
        float4 bb1 = b4[2 * c + 1];
        float4 o0, o1;
        o0.x = fmaxf(fmaf(a0.x, dn, bb0.x), 0.f);
        o0.y = fmaxf(fmaf(a0.y, dn, bb0.y), 0.f);
        o0.z = fmaxf(fmaf(a0.z, dn, bb0.z), 0.f);
        o0.w = fmaxf(fmaf(a0.w, dn, bb0.w), 0.f);
        o1.x = fmaxf(fmaf(a1.x, dn, bb1.x), 0.f);
        o1.y = fmaxf(fmaf(a1.y, dn, bb1.y), 0.f);
        o1.z = fmaxf(fmaf(a1.z, dn, bb1.z), 0.f);
        o1.w = fmaxf(fmaf(a1.w, dn, bb1.w), 0.f);
        out4[(size_t)node * 16 + 2 * c] = o0;
        out4[(size_t)node * 16 + 2 * c + 1] = o1;
    }
}

// ---------------- launch ----------------

extern "C" void kernel_launch(void* const* d_in, const int* in_sizes, int n_in,
                              void* d_out, int out_size, void* d_ws, size_t ws_size,
                              hipStream_t stream) {
    const float* z = (const float*)d_in[0];
    const int* ei  = (const int*)d_in[1];
    const float* W = (const float*)d_in[2];
    const float* b = (const float*)d_in[3];
    float* out = (float*)d_out;

    const int N = in_sizes[0] / DD;
    const int E = in_sizes[1] / 2;
    const int* src = ei;
    const int* dst = ei + E;

    const int NBK = (N + GBKT - 1) >> BSH;

    // workspace layout
    unsigned short* ybf = (unsigned short*)d_ws;      // 64N ushorts (bf16)
    int*   bcur  = (int*)(ybf + (size_t)64 * N);      // NBK (counts)
    int*   bp    = bcur + NBK;                        // NBK*CAP

    hipMemsetAsync(bcur, 0, sizeof(int) * NBK, stream);
    part_k<<<(E + TILE - 1) / TILE, PTHREADS, 0, stream>>>(src, dst, bcur, bp, E, NBK);
    dg_k<<<NBK, 512, 0, stream>>>(bp, bcur, z, W, (ushort4*)ybf, N);
    bg_k<<<NBK, 256, 0, stream>>>((const uint4*)ybf, bp, bcur,
                                  (const float4*)b, (float4*)out, N);
}